// Round 1
// baseline (423.545 us; speedup 1.0000x reference)
//
#include <hip/hip_runtime.h>

#define DT_C 0.01f

typedef unsigned short u16;
typedef __bf16 bf8 __attribute__((ext_vector_type(8)));
typedef float f32x4 __attribute__((ext_vector_type(4)));

__device__ __forceinline__ u16 f2bf(float f) {
  unsigned u = __float_as_uint(f);
  unsigned r = (u + 0x7FFFu + ((u >> 16) & 1u)) >> 16;
  return (u16)r;
}
__device__ __forceinline__ float bflo(unsigned w) { return __uint_as_float(w << 16); }
__device__ __forceinline__ float bfhi(unsigned w) { return __uint_as_float(w & 0xFFFF0000u); }

// ---------------- kernel 1: context encoder -> h (bf16) ----------------
__global__ __launch_bounds__(512) void k_ctxt(const float* __restrict__ xh,
                                              const float* __restrict__ uh,
                                              const float* __restrict__ Wc,
                                              const float* __restrict__ bc,
                                              u16* __restrict__ h_bf) {
  __shared__ float m[96];
  int b = blockIdx.x, t = threadIdx.x;
  if (t < 96) {
    float s = 0.f;
    if (t < 64) {
      const float* p = xh + (size_t)b * 2048 + t;
      for (int tt = 0; tt < 32; ++tt) s += p[tt * 64];
    } else {
      const float* p = uh + (size_t)b * 1024 + (t - 64);
      for (int tt = 0; tt < 32; ++tt) s += p[tt * 32];
    }
    m[t] = s * (1.0f / 32.0f);
  }
  __syncthreads();
  float acc = bc[t];
  #pragma unroll 8
  for (int s = 0; s < 96; ++s) acc += m[s] * Wc[s * 512 + t];
  h_bf[b * 512 + t] = f2bf(tanhf(acc));
}

// ------- kernel 2: head GEMM out[256,N] = h(bf16) @ W(f32, cvt bf16) + b -------
// block 256 (4 waves), WG tile 256(M) x 64(N), K=512 in 16 chunks of 32.
// wave w owns rows [64w,64w+64); MFMA 16x16x32_bf16; LDS rows padded to 40 u16.
__global__ __launch_bounds__(256) void k_head(const u16* __restrict__ hb,
                                              const float* __restrict__ W,
                                              const float* __restrict__ bias,
                                              float* __restrict__ out, int N) {
  __shared__ __align__(16) u16 Al[256 * 40];
  __shared__ __align__(16) u16 Bl[64 * 40];
  int t = threadIdx.x;
  int n0 = blockIdx.x * 64;
  int w = t >> 6, l = t & 63;
  int r16 = l & 15, kb = (l >> 4) * 8;
  f32x4 acc[4][4];
  #pragma unroll
  for (int i = 0; i < 4; ++i)
    #pragma unroll
    for (int j = 0; j < 4; ++j) acc[i][j] = f32x4{0.f, 0.f, 0.f, 0.f};
  for (int kk = 0; kk < 16; ++kk) {
    int k0 = kk * 32;
    {  // stage A: h rows 256 x 32 (already bf16 in ws)
      int row = t >> 2, kq = t & 3;
      #pragma unroll
      for (int p = 0; p < 4; ++p) {
        int rr = row + 64 * p;
        *(uint4*)(&Al[rr * 40 + kq * 8]) = *(const uint4*)(hb + rr * 512 + k0 + kq * 8);
      }
    }
    {  // stage B: W[k0..+32][n0..+64] -> Bl[n][k] bf16 (transpose + cvt)
      int n = t & 63, kp0 = t >> 6;
      #pragma unroll
      for (int r2 = 0; r2 < 4; ++r2) {
        int kp = kp0 * 4 + r2;
        long k = k0 + kp * 2;
        float f0 = W[k * N + n0 + n];
        float f1 = W[(k + 1) * N + n0 + n];
        unsigned pk = ((unsigned)f2bf(f1) << 16) | (unsigned)f2bf(f0);
        *(unsigned*)(&Bl[n * 40 + kp * 2]) = pk;
      }
    }
    __syncthreads();
    bf8 afr[4], bfr[4];
    #pragma unroll
    for (int mf = 0; mf < 4; ++mf)
      afr[mf] = __builtin_bit_cast(bf8, *(const uint4*)(&Al[(w * 64 + mf * 16 + r16) * 40 + kb]));
    #pragma unroll
    for (int nf = 0; nf < 4; ++nf)
      bfr[nf] = __builtin_bit_cast(bf8, *(const uint4*)(&Bl[(nf * 16 + r16) * 40 + kb]));
    #pragma unroll
    for (int mf = 0; mf < 4; ++mf)
      #pragma unroll
      for (int nf = 0; nf < 4; ++nf)
        acc[mf][nf] = __builtin_amdgcn_mfma_f32_16x16x32_bf16(afr[mf], bfr[nf], acc[mf][nf], 0, 0, 0);
    __syncthreads();
  }
  #pragma unroll
  for (int nf = 0; nf < 4; ++nf) {
    int col = n0 + nf * 16 + r16;
    float bv = bias[col];
    #pragma unroll
    for (int mf = 0; mf < 4; ++mf) {
      int row0 = w * 64 + mf * 16 + (l >> 4) * 4;
      #pragma unroll
      for (int r = 0; r < 4; ++r)
        out[(long)(row0 + r) * N + col] = acc[mf][nf][r] + bv;
    }
  }
}

// ---------------- kernel 3: rollout scan, one WG per batch ----------------
// Ext[j][i] (bf16): j<256 -> dt*A_ct[i][j], j in [256,288) -> B_mat[i][j-256]
// z_{k+1}[i] = z_k[i] + sum_j Ext[j][i]*zext[j],  zext = [z_k ; u_k]
__global__ __launch_bounds__(512) void k_scan(const float* __restrict__ Act,
                                              const float* __restrict__ Bm,
                                              const float* __restrict__ x_init,
                                              const float* __restrict__ u_fut,
                                              const float* __restrict__ We,
                                              const float* __restrict__ be,
                                              float* __restrict__ zt) {
  __shared__ __align__(16) u16 Ext[288 * 256];
  __shared__ __align__(16) float zext[288];
  __shared__ __align__(16) float part[8][256];
  int b = blockIdx.x, t = threadIdx.x;
  const float* A = Act + (size_t)b * 65536;
  {
    int i = t >> 1;
    #pragma unroll 4
    for (int rep = 0; rep < 32; ++rep) {
      int jq = (t & 1) + 2 * rep;
      float4 v = *(const float4*)(A + i * 256 + jq * 4);
      Ext[(jq * 4 + 0) * 256 + i] = f2bf(v.x * DT_C);
      Ext[(jq * 4 + 1) * 256 + i] = f2bf(v.y * DT_C);
      Ext[(jq * 4 + 2) * 256 + i] = f2bf(v.z * DT_C);
      Ext[(jq * 4 + 3) * 256 + i] = f2bf(v.w * DT_C);
    }
  }
  if (t < 256) {
    const float* Bp = Bm + (size_t)b * 8192 + t * 32;
    #pragma unroll
    for (int cq = 0; cq < 8; ++cq) {
      float4 v = *(const float4*)(Bp + cq * 4);
      Ext[(256 + cq * 4 + 0) * 256 + t] = f2bf(v.x);
      Ext[(256 + cq * 4 + 1) * 256 + t] = f2bf(v.y);
      Ext[(256 + cq * 4 + 2) * 256 + t] = f2bf(v.z);
      Ext[(256 + cq * 4 + 3) * 256 + t] = f2bf(v.w);
    }
    float z = be[t];
    const float* xi = x_init + b * 64;
    #pragma unroll 8
    for (int s = 0; s < 64; ++s) z += xi[s] * We[s * 256 + t];
    zext[t] = z;
    zt[(size_t)b * 33024 + t] = z;
  } else if (t < 288) {
    zext[t] = u_fut[((size_t)b * 128) * 32 + (t - 256)];
  }
  __syncthreads();
  int jg = t >> 6, ti = t & 63;
  const u16* ep = Ext + ti * 4;
  for (int k = 0; k < 128; ++k) {
    float uv = 0.f;
    if (t >= 256 && t < 288 && k < 127)
      uv = u_fut[((size_t)b * 128 + k + 1) * 32 + (t - 256)];
    float a0 = 0.f, a1 = 0.f, a2 = 0.f, a3 = 0.f;
    int j0 = jg * 36;
    #pragma unroll 6
    for (int jj = j0; jj < j0 + 36; ++jj) {
      float s = zext[jj];
      uint2 w2 = *(const uint2*)(ep + jj * 256);
      a0 += s * bflo(w2.x);
      a1 += s * bfhi(w2.x);
      a2 += s * bflo(w2.y);
      a3 += s * bfhi(w2.y);
    }
    *(float4*)(&part[jg][ti * 4]) = make_float4(a0, a1, a2, a3);
    __syncthreads();
    if (t < 256) {
      float nz = zext[t];
      #pragma unroll
      for (int g = 0; g < 8; ++g) nz += part[g][t];
      zext[t] = nz;
      zt[(size_t)b * 33024 + (size_t)(k + 1) * 256 + t] = nz;
    } else if (t < 288) {
      zext[t] = uv;
    }
    __syncthreads();
  }
}

// ---------------- kernel 4: x_traj = z_traj @ W_dec + b_dec ----------------
__global__ __launch_bounds__(256) void k_dec(const float* __restrict__ z,
                                             const float* __restrict__ Wd,
                                             const float* __restrict__ bd,
                                             float* __restrict__ x) {
  __shared__ __align__(16) u16 Wl[256 * 64];
  __shared__ float zl[16 * 258];
  int t = threadIdx.x;
  long r0 = (long)blockIdx.x * 16;
  #pragma unroll 8
  for (int r = 0; r < 64; ++r) {
    int f = t + 256 * r;
    Wl[f] = f2bf(Wd[f]);
  }
  const float* zsrc = z + r0 * 256;
  #pragma unroll
  for (int r = 0; r < 16; ++r) {
    int f = t + 256 * r;
    int row = f >> 8, n = f & 255;
    zl[row * 258 + n] = zsrc[f];
  }
  __syncthreads();
  int dq = t & 15, rg = t >> 4;
  int d0 = dq * 4;
  float4 bv = *(const float4*)(bd + d0);
  float a0 = bv.x, a1 = bv.y, a2 = bv.z, a3 = bv.w;
  const float* zr = &zl[rg * 258];
  #pragma unroll 8
  for (int n = 0; n < 256; ++n) {
    float zv = zr[n];
    uint2 w2 = *(const uint2*)(&Wl[n * 64 + d0]);
    a0 += zv * bflo(w2.x);
    a1 += zv * bfhi(w2.x);
    a2 += zv * bflo(w2.y);
    a3 += zv * bfhi(w2.y);
  }
  *(float4*)(x + (r0 + rg) * 64 + d0) = make_float4(a0, a1, a2, a3);
}

// ------- kernel 5: z = x @ W_enc + b_enc for x_traj (y=0) and x_gt (y=1) -------
__global__ __launch_bounds__(256) void k_enc(const float* __restrict__ xa,
                                             const float* __restrict__ x_init,
                                             const float* __restrict__ x_fut,
                                             const float* __restrict__ Wen,
                                             const float* __restrict__ ben,
                                             float* __restrict__ z_re,
                                             float* __restrict__ x_gt,
                                             float* __restrict__ z_gt) {
  __shared__ __align__(16) u16 Wl[64 * 256];
  __shared__ float xr[16 * 66];
  int t = threadIdx.x;
  bool gt = (blockIdx.y == 1);
  long r0 = (long)blockIdx.x * 16;
  #pragma unroll 8
  for (int r = 0; r < 64; ++r) {
    int f = t + 256 * r;
    Wl[f] = f2bf(Wen[f]);
  }
  #pragma unroll
  for (int r = 0; r < 4; ++r) {
    int f = t + 256 * r;
    int row = f >> 6, s = f & 63;
    long gr = r0 + row;
    float v;
    if (!gt) {
      v = xa[gr * 64 + s];
    } else {
      long bb = gr / 129, kk = gr - bb * 129;
      v = (kk == 0) ? x_init[bb * 64 + s] : x_fut[(bb * 128 + (kk - 1)) * 64 + s];
      x_gt[gr * 64 + s] = v;
    }
    xr[row * 66 + s] = v;
  }
  __syncthreads();
  int iq = t & 63, rg = t >> 6;
  int i0 = iq * 4;
  float4 bv = *(const float4*)(ben + i0);
  float* zo = gt ? z_gt : z_re;
  #pragma unroll
  for (int rr = 0; rr < 4; ++rr) {
    int row = rg * 4 + rr;
    float a0 = bv.x, a1 = bv.y, a2 = bv.z, a3 = bv.w;
    const float* xp = &xr[row * 66];
    #pragma unroll 8
    for (int s = 0; s < 64; ++s) {
      float xv = xp[s];
      uint2 w2 = *(const uint2*)(&Wl[s * 256 + i0]);
      a0 += xv * bflo(w2.x);
      a1 += xv * bfhi(w2.x);
      a2 += xv * bflo(w2.y);
      a3 += xv * bfhi(w2.y);
    }
    *(float4*)(zo + (r0 + row) * 256 + i0) = make_float4(a0, a1, a2, a3);
  }
}

extern "C" void kernel_launch(void* const* d_in, const int* in_sizes, int n_in,
                              void* d_out, int out_size, void* d_ws, size_t ws_size,
                              hipStream_t stream) {
  const float* xh     = (const float*)d_in[0];
  const float* uh     = (const float*)d_in[1];
  const float* x_init = (const float*)d_in[2];
  const float* x_fut  = (const float*)d_in[3];
  const float* u_fut  = (const float*)d_in[4];
  // d_in[5] = n_steps (128, fixed)
  const float* Wc = (const float*)d_in[6];
  const float* bc = (const float*)d_in[7];
  const float* WA = (const float*)d_in[8];
  const float* bA = (const float*)d_in[9];
  const float* WB = (const float*)d_in[10];
  const float* bB = (const float*)d_in[11];
  const float* We = (const float*)d_in[12];
  const float* be = (const float*)d_in[13];
  const float* Wd = (const float*)d_in[14];
  const float* bd = (const float*)d_in[15];

  float* out    = (float*)d_out;
  float* z_traj = out;                 // [256,129,256]
  float* x_traj = out + 8454144;       // [256,129,64]
  float* A_ct   = out + 10567680;      // [256,256,256]
  float* B_mat  = out + 27344896;      // [256,256,32]
  float* z_re   = out + 29442048;      // [256,129,256]
  float* x_gt   = out + 37896192;      // [256,129,64]
  float* z_gt   = out + 40009728;      // [256,129,256]

  u16* h_bf = (u16*)d_ws;              // 256x512 bf16

  hipLaunchKernelGGL(k_ctxt, dim3(256), dim3(512), 0, stream, xh, uh, Wc, bc, h_bf);
  hipLaunchKernelGGL(k_head, dim3(1024), dim3(256), 0, stream, h_bf, WA, bA, A_ct, 65536);
  hipLaunchKernelGGL(k_head, dim3(128), dim3(256), 0, stream, h_bf, WB, bB, B_mat, 8192);
  hipLaunchKernelGGL(k_scan, dim3(256), dim3(512), 0, stream, A_ct, B_mat, x_init, u_fut, We, be, z_traj);
  hipLaunchKernelGGL(k_dec, dim3(2064), dim3(256), 0, stream, z_traj, Wd, bd, x_traj);
  hipLaunchKernelGGL(k_enc, dim3(2064, 2), dim3(256), 0, stream, x_traj, x_init, x_fut, We, be, z_re, x_gt, z_gt);
}